// Round 2
// baseline (225.793 us; speedup 1.0000x reference)
//
#include <hip/hip_runtime.h>
#include <hip/hip_cooperative_groups.h>
#include <math.h>

namespace cg = cooperative_groups;

#define N_BOX 8192
#define NW 128              // 8192 / 64 words per keep-mask row
#define LCAP 24576          // edges staged in LDS (96 KiB)
#define ECAP_MAX (1 << 21)  // max edges in global buffer (8 MiB)
#define NBLK 128            // cooperative grid: 128 blocks (<=256 CUs, 1 blk/CU)
#define NTHR 512
#define NCH 8               // candidate chunks for rank stage
#define CH 1024             // N_BOX / NCH candidates per chunk
#define THR_C 0.7f
#define IOU_THR_C 0.5f
#define EPS_C 1e-9f

// SCALER = max(3508/1280, 2480/1280) computed in double then rounded to f32,
// matching numpy/jax float32 weak-typed scalar promotion.
__device__ __constant__ float kScaler = (float)(3508.0 / 1280.0);

static __device__ __forceinline__ unsigned long long make_key(const float* conf, int i) {
    float c0 = conf[2 * i], c1 = conf[2 * i + 1];
    bool valid = (c0 > THR_C) || (c1 > THR_C);
    float ms = valid ? fmaxf(c0, c1) : -INFINITY;
    unsigned int u = __float_as_uint(ms);
    unsigned int m = (u & 0x80000000u) ? ~u : (u | 0x80000000u); // ascending map
    unsigned int d = ~m;                                          // descending key
    return ((unsigned long long)d << 32) | (unsigned int)i;
}

// ---------------------------------------------------------------------------
// Fully fused pipeline: key -> rank -> scatter -> pair -> scan -> out, with
// cooperative grid syncs between stages (replaces 5 inter-kernel gaps).
// Stage logic is bit-identical to the verified 6-kernel pipeline.
// ---------------------------------------------------------------------------
__global__ __launch_bounds__(NTHR, 1) void fused_kernel(
    const float* __restrict__ conf,
    const float* __restrict__ bboxes,
    float* __restrict__ out,
    unsigned long long* __restrict__ keys,
    int* __restrict__ partial,
    float4* __restrict__ sb,
    unsigned int* __restrict__ order,
    unsigned int* __restrict__ edges,
    int* __restrict__ ecntE,
    int* __restrict__ nvD,
    unsigned long long* __restrict__ keepK,
    int ecap)
{
    cg::grid_group grid = cg::this_grid();

    __shared__ unsigned int eL[LCAP];                       // 96 KiB (scan, blk 0)
    __shared__ unsigned long long kL[NW], tL[NW], vL[NW];   // 3 KiB
    __shared__ int chg[3];
    __shared__ float4 cb[64];                               // 1 KiB (pair)
    __shared__ float carea[64];

    const int t = threadIdx.x;
    const int b = blockIdx.x;
    const int tid = b * NTHR + t;

    // ---- Stage A: build sort keys, zero counters ----
    if (tid < N_BOX) keys[tid] = make_key(conf, tid);
    if (tid == 0) { *ecntE = 0; *nvD = 0; }
    grid.sync();

    // ---- Stage B: rank partial counts ----
    // rank(i) = #{j : key_j < key_i} is an exact stable permutation (keys
    // unique). block b = (element chunk b>>3 of 512, candidate chunk b&7 of
    // 1024). Candidate address is wave-uniform -> scalar/broadcast loads.
    {
        const int by = b & (NCH - 1);
        const int bx = b >> 3;
        const int i = bx * NTHR + t;
        const unsigned long long ki = keys[i];
        const ulonglong4* kp = (const ulonglong4*)(keys + by * CH);
        int c0 = 0, c1 = 0, c2 = 0, c3 = 0;
#pragma unroll 4
        for (int l = 0; l < CH / 4; ++l) {
            ulonglong4 kq = kp[l];
            c0 += (kq.x < ki) ? 1 : 0;
            c1 += (kq.y < ki) ? 1 : 0;
            c2 += (kq.z < ki) ? 1 : 0;
            c3 += (kq.w < ki) ? 1 : 0;
        }
        partial[by * N_BOX + i] = (c0 + c1) + (c2 + c3);
    }
    grid.sync();

    // ---- Stage C: sum ranks, scatter boxes/order, count valid ----
    // Valid boxes land exactly in ranks [0, nv). Invalid boxes are never
    // scattered (their output rows are forced zeros downstream).
    if (tid < N_BOX) {
        int r = 0;
#pragma unroll
        for (int c = 0; c < NCH; ++c) r += partial[c * N_BOX + tid];
        float c0 = conf[2 * tid], c1 = conf[2 * tid + 1];
        bool valid = (c0 > THR_C) || (c1 > THR_C);
        if (valid) {
            sb[r] = ((const float4*)bboxes)[tid];
            order[r] = (unsigned int)tid;
        }
        unsigned long long vb = __ballot(valid);
        if ((t & 63) == 0) atomicAdd(nvD, __popcll(vb));
    }
    grid.sync();

    const int nv = *nvD;

    // ---- Stage D: compact edge list over the nv x nv upper triangle ----
    // Block b owns j-word b (64 candidates) for its lifetime: stage the
    // candidate tile ONCE, sweep all 16 i-tiles of 512 rows against it.
    {
        const int jbase = b << 6;
        if (jbase < nv) {
            if (t < 64) {
                float4 c = sb[jbase + t];
                cb[t] = c;
                carea[t] = (c.z - c.x) * (c.w - c.y);
            }
            __syncthreads();
            for (int ib = 0; ib < 16; ++ib) {
                int ibase = ib << 9;
                if (ibase >= nv) break;                 // uniform
                if (jbase + 63 <= ibase) continue;      // uniform
                int i = ibase + t;
                unsigned long long bits = 0ull;
                if (i < nv && jbase + 63 > i) {
                    float4 r = sb[i];
                    float ra = (r.z - r.x) * (r.w - r.y);
#pragma unroll 8
                    for (int bb = 0; bb < 64; ++bb) {
                        float4 c = cb[bb];
                        float iw = fminf(r.z, c.z) - fmaxf(r.x, c.x);
                        float ih = fminf(r.w, c.w) - fmaxf(r.y, c.y);
                        iw = fmaxf(iw, 0.0f);
                        ih = fmaxf(ih, 0.0f);
                        float inter = iw * ih;
                        float iou = inter / (ra + carea[bb] - inter + EPS_C);
                        if ((iou > IOU_THR_C) && ((jbase + bb) > i)) bits |= (1ull << bb);
                    }
                }
                // drop targets >= nv (invalid; also masks poison IoUs)
                unsigned long long tmask = (jbase + 64 <= nv) ? ~0ull
                                           : ((1ull << (nv - jbase)) - 1ull);
                unsigned long long ebits = bits & tmask;
                int lane = t & 63;
                int ec = __popcll(ebits);
                int pre = ec;
#pragma unroll
                for (int d = 1; d < 64; d <<= 1) {
                    int vv = __shfl_up(pre, d, 64);
                    if (lane >= d) pre += vv;
                }
                int tot = __shfl(pre, 63, 64);
                if (tot > 0) {
                    int base = 0;
                    if (lane == 63) base = atomicAdd(ecntE, tot);
                    base = __shfl(base, 63, 64);
                    int idx = base + pre - ec;
                    unsigned long long tb = ebits;
                    while (tb) {
                        int bb = __builtin_ctzll(tb); tb &= tb - 1;
                        if (idx < ecap)
                            edges[idx] = ((unsigned int)i << 13) | (unsigned int)(jbase + bb);
                        ++idx;
                    }
                }
            }
        }
    }
    grid.sync();

    // ---- Stage E: Jacobi-iterated greedy NMS (block 0 only) ----
    // Greedy NMS is the unique fixpoint of k[i] = v[i] & ~OR_{j<i,e(j,i)} k[j];
    // k_new == k_old certifies convergence. valid == rank < nv.
    if (b == 0) {
        const int cnt = *ecntE;
        if (t < NW) {
            int lo = t << 6;
            unsigned long long v;
            if (nv >= lo + 64)      v = ~0ull;
            else if (nv <= lo)      v = 0ull;
            else                    v = (1ull << (nv - lo)) - 1ull;
            vL[t] = v; kL[t] = v;
        }
        if (t == 0) { chg[0] = 0; chg[1] = 0; chg[2] = 0; }
        if (cnt <= ecap) {
            int lim = cnt < LCAP ? cnt : LCAP;
            for (int e = t; e < lim; e += NTHR) eL[e] = edges[e];
        }
        __syncthreads();
        if (cnt <= ecap) {
            for (int it = 0; it < N_BOX; ++it) {
                if (t < NW) tL[t] = 0ull;
                __syncthreads();
                for (int e = t; e < cnt; e += NTHR) {
                    unsigned int ed = (e < LCAP) ? eL[e] : edges[e];
                    int src = (int)(ed >> 13);
                    if ((kL[src >> 6] >> (src & 63)) & 1ull) {
                        int tg = (int)(ed & 8191u);
                        atomicOr(&tL[tg >> 6], 1ull << (tg & 63));
                    }
                }
                __syncthreads();
                if (t < NW) {
                    unsigned long long nk = vL[t] & ~tL[t];
                    if (nk != kL[t]) chg[it % 3] = 1;
                    kL[t] = nk;
                }
                if (t == 0) chg[(it + 2) % 3] = 0;   // reset 2 barriers before reuse
                __syncthreads();
                if (chg[it % 3] == 0) break;         // uniform: read after barrier
            }
        } else {
            // fallback: serial greedy over ranks [0,nv), IoU on the fly
            if (t < NW) tL[t] = 0ull;
            __syncthreads();
            if (t < 64) {
                int lane = t;
                for (int i = 0; i < nv - 1; ++i) {
                    bool rem = (tL[i >> 6] >> (i & 63)) & 1ull;
                    if (!rem) {
                        float4 r = sb[i];
                        float ra = (r.z - r.x) * (r.w - r.y);
                        for (int j = i + 1 + lane; j < nv; j += 64) {
                            float4 c = sb[j];
                            float ca = (c.z - c.x) * (c.w - c.y);
                            float iw = fminf(r.z, c.z) - fmaxf(r.x, c.x);
                            float ih = fminf(r.w, c.w) - fmaxf(r.y, c.y);
                            iw = fmaxf(iw, 0.0f);
                            ih = fmaxf(ih, 0.0f);
                            float inter = iw * ih;
                            float iou = inter / (ra + ca - inter + EPS_C);
                            if (iou > IOU_THR_C) atomicOr(&tL[j >> 6], 1ull << (j & 63));
                        }
                    }
                }
            }
            __syncthreads();
            if (t < NW) kL[t] = vL[t] & ~tL[t];
        }
        __syncthreads();
        if (t < NW) keepK[t] = kL[t];
    }
    grid.sync();

    // ---- Stage F: write (N,6) output ----
    // Kept rows = [boxes*SCALER, conf]; all other rows are exactly 0.0 in the
    // reference, so write literal zeros (sb/order at ranks >= nv hold poison).
    if (tid < N_BOX) {
        bool kept = (keepK[tid >> 6] >> (tid & 63)) & 1ull;
        if (kept) {
            float4 bx = sb[tid];
            unsigned int o = order[tid];
            out[tid * 6 + 0] = bx.x * kScaler;
            out[tid * 6 + 1] = bx.y * kScaler;
            out[tid * 6 + 2] = bx.z * kScaler;
            out[tid * 6 + 3] = bx.w * kScaler;
            out[tid * 6 + 4] = conf[2 * o];
            out[tid * 6 + 5] = conf[2 * o + 1];
        } else {
            out[tid * 6 + 0] = 0.0f;
            out[tid * 6 + 1] = 0.0f;
            out[tid * 6 + 2] = 0.0f;
            out[tid * 6 + 3] = 0.0f;
            out[tid * 6 + 4] = 0.0f;
            out[tid * 6 + 5] = 0.0f;
        }
    }
}

// ===========================================================================
// Fallback path (verified round-1 pipeline) — used only if the cooperative
// launch is rejected by the runtime. Identical math.
// ===========================================================================
__global__ __launch_bounds__(256) void key_kernel(const float* __restrict__ conf,
                                                  unsigned long long* __restrict__ keys,
                                                  int* __restrict__ ecntE,
                                                  int* __restrict__ nvD) {
    int i = blockIdx.x * 256 + threadIdx.x;
    if (i == 0) { *ecntE = 0; *nvD = 0; }
    keys[i] = make_key(conf, i);
}

__global__ __launch_bounds__(256) void rank_kernel(const unsigned long long* __restrict__ keys,
                                                   int* __restrict__ partial) {
    int i = blockIdx.x * 256 + threadIdx.x;
    unsigned long long ki = keys[i];
    const ulonglong4* kp = (const ulonglong4*)(keys + blockIdx.y * CH);
    int c0 = 0, c1 = 0, c2 = 0, c3 = 0;
#pragma unroll 4
    for (int l = 0; l < CH / 4; ++l) {
        ulonglong4 kq = kp[l];
        c0 += (kq.x < ki) ? 1 : 0;
        c1 += (kq.y < ki) ? 1 : 0;
        c2 += (kq.z < ki) ? 1 : 0;
        c3 += (kq.w < ki) ? 1 : 0;
    }
    partial[blockIdx.y * N_BOX + i] = (c0 + c1) + (c2 + c3);
}

__global__ __launch_bounds__(256) void scatter_kernel(const float* __restrict__ conf,
                                                      const float* __restrict__ bboxes,
                                                      const int* __restrict__ partial,
                                                      float4* __restrict__ sb,
                                                      unsigned int* __restrict__ order,
                                                      int* __restrict__ nvD) {
    int i = blockIdx.x * 256 + threadIdx.x;
    int r = 0;
#pragma unroll
    for (int c = 0; c < NCH; ++c) r += partial[c * N_BOX + i];
    float c0 = conf[2 * i], c1 = conf[2 * i + 1];
    bool valid = (c0 > THR_C) || (c1 > THR_C);
    if (valid) {
        sb[r] = ((const float4*)bboxes)[i];
        order[r] = (unsigned int)i;
    }
    unsigned long long vb = __ballot(valid);
    if ((threadIdx.x & 63) == 0) atomicAdd(nvD, __popcll(vb));
}

__global__ void pair_kernel(const float4* __restrict__ sb,
                            const int* __restrict__ nvD,
                            unsigned int* __restrict__ edges,
                            int* __restrict__ ecntE,
                            int ecap) {
    int w = blockIdx.y;
    int jbase = w << 6;
    int ibase = blockIdx.x * 256;
    int nv = *nvD;
    if (ibase >= nv || jbase >= nv || jbase + 63 <= ibase) return;
    __shared__ float4 cb[64];
    __shared__ float carea[64];
    if (threadIdx.x < 64) {
        float4 c = sb[jbase + threadIdx.x];
        cb[threadIdx.x] = c;
        carea[threadIdx.x] = (c.z - c.x) * (c.w - c.y);
    }
    __syncthreads();
    int i = ibase + threadIdx.x;
    unsigned long long bits = 0ull;
    if (i < nv && jbase + 63 > i) {
        float4 r = sb[i];
        float ra = (r.z - r.x) * (r.w - r.y);
#pragma unroll 8
        for (int b = 0; b < 64; ++b) {
            float4 c = cb[b];
            float iw = fminf(r.z, c.z) - fmaxf(r.x, c.x);
            float ih = fminf(r.w, c.w) - fmaxf(r.y, c.y);
            iw = fmaxf(iw, 0.0f);
            ih = fmaxf(ih, 0.0f);
            float inter = iw * ih;
            float iou = inter / (ra + carea[b] - inter + EPS_C);
            if ((iou > IOU_THR_C) && ((jbase + b) > i)) bits |= (1ull << b);
        }
    }
    unsigned long long tmask = (jbase + 64 <= nv) ? ~0ull
                               : ((1ull << (nv - jbase)) - 1ull);
    unsigned long long ebits = bits & tmask;
    int lane = threadIdx.x & 63;
    int ec = __popcll(ebits);
    int pre = ec;
#pragma unroll
    for (int d = 1; d < 64; d <<= 1) {
        int vv = __shfl_up(pre, d, 64);
        if (lane >= d) pre += vv;
    }
    int tot = __shfl(pre, 63, 64);
    if (tot > 0) {
        int base = 0;
        if (lane == 63) base = atomicAdd(ecntE, tot);
        base = __shfl(base, 63, 64);
        int idx = base + pre - ec;
        unsigned long long tb = ebits;
        while (tb) {
            int b = __builtin_ctzll(tb); tb &= tb - 1;
            if (idx < ecap) edges[idx] = ((unsigned int)i << 13) | (unsigned int)(jbase + b);
            ++idx;
        }
    }
}

__global__ __launch_bounds__(512) void scan_kernel(const unsigned int* __restrict__ edges,
                                                   const int* __restrict__ ecntE,
                                                   const int* __restrict__ nvD,
                                                   const float4* __restrict__ sb,
                                                   unsigned long long* __restrict__ keepK,
                                                   int ecap) {
    __shared__ unsigned int eL[LCAP];
    __shared__ unsigned long long kL[NW], tL[NW], vL[NW];
    __shared__ int chg[3];
    int t = threadIdx.x;
    int cnt = *ecntE;
    int nv = *nvD;
    if (t < NW) {
        int lo = t << 6;
        unsigned long long v;
        if (nv >= lo + 64)      v = ~0ull;
        else if (nv <= lo)      v = 0ull;
        else                    v = (1ull << (nv - lo)) - 1ull;
        vL[t] = v; kL[t] = v;
    }
    if (t == 0) { chg[0] = 0; chg[1] = 0; chg[2] = 0; }
    if (cnt <= ecap) {
        int lim = cnt < LCAP ? cnt : LCAP;
        for (int e = t; e < lim; e += 512) eL[e] = edges[e];
    }
    __syncthreads();
    if (cnt <= ecap) {
        for (int it = 0; it < N_BOX; ++it) {
            if (t < NW) tL[t] = 0ull;
            __syncthreads();
            for (int e = t; e < cnt; e += 512) {
                unsigned int ed = (e < LCAP) ? eL[e] : edges[e];
                int src = (int)(ed >> 13);
                if ((kL[src >> 6] >> (src & 63)) & 1ull) {
                    int tg = (int)(ed & 8191u);
                    atomicOr(&tL[tg >> 6], 1ull << (tg & 63));
                }
            }
            __syncthreads();
            if (t < NW) {
                unsigned long long nk = vL[t] & ~tL[t];
                if (nk != kL[t]) chg[it % 3] = 1;
                kL[t] = nk;
            }
            if (t == 0) chg[(it + 2) % 3] = 0;
            __syncthreads();
            if (chg[it % 3] == 0) break;
        }
    } else {
        if (t < NW) tL[t] = 0ull;
        __syncthreads();
        if (t < 64) {
            int lane = t;
            for (int i = 0; i < nv - 1; ++i) {
                bool rem = (tL[i >> 6] >> (i & 63)) & 1ull;
                if (!rem) {
                    float4 r = sb[i];
                    float ra = (r.z - r.x) * (r.w - r.y);
                    for (int j = i + 1 + lane; j < nv; j += 64) {
                        float4 c = sb[j];
                        float ca = (c.z - c.x) * (c.w - c.y);
                        float iw = fminf(r.z, c.z) - fmaxf(r.x, c.x);
                        float ih = fminf(r.w, c.w) - fmaxf(r.y, c.y);
                        iw = fmaxf(iw, 0.0f);
                        ih = fmaxf(ih, 0.0f);
                        float inter = iw * ih;
                        float iou = inter / (ra + ca - inter + EPS_C);
                        if (iou > IOU_THR_C) atomicOr(&tL[j >> 6], 1ull << (j & 63));
                    }
                }
            }
        }
        __syncthreads();
        if (t < NW) kL[t] = vL[t] & ~tL[t];
    }
    __syncthreads();
    if (t < NW) keepK[t] = kL[t];
}

__global__ void out_kernel(const float4* __restrict__ sb,
                           const unsigned long long* __restrict__ keepK,
                           const unsigned int* __restrict__ order,
                           const float* __restrict__ conf,
                           float* __restrict__ out) {
    int i = blockIdx.x * 256 + threadIdx.x;
    bool kept = (keepK[i >> 6] >> (i & 63)) & 1ull;
    if (kept) {
        float4 b = sb[i];
        unsigned int o = order[i];
        out[i * 6 + 0] = b.x * kScaler;
        out[i * 6 + 1] = b.y * kScaler;
        out[i * 6 + 2] = b.z * kScaler;
        out[i * 6 + 3] = b.w * kScaler;
        out[i * 6 + 4] = conf[2 * o];
        out[i * 6 + 5] = conf[2 * o + 1];
    } else {
        out[i * 6 + 0] = 0.0f;
        out[i * 6 + 1] = 0.0f;
        out[i * 6 + 2] = 0.0f;
        out[i * 6 + 3] = 0.0f;
        out[i * 6 + 4] = 0.0f;
        out[i * 6 + 5] = 0.0f;
    }
}

extern "C" void kernel_launch(void* const* d_in, const int* in_sizes, int n_in,
                              void* d_out, int out_size, void* d_ws, size_t ws_size,
                              hipStream_t stream) {
    const float* cls_conf = (const float*)d_in[0];   // (8192, 2)
    const float* bboxes   = (const float*)d_in[1];   // (8192, 4)
    float* out = (float*)d_out;                      // (8192, 6)

    char* ws = (char*)d_ws;
    unsigned long long* keys    = (unsigned long long*)(ws + 0);        //  64 KiB
    int*                partial = (int*)(ws + 65536);                   // 256 KiB
    float4*             sb      = (float4*)(ws + 327680);               // 128 KiB
    unsigned int*       order   = (unsigned int*)(ws + 458752);         //  32 KiB
    int*                ecntE   = (int*)(ws + 491520);                  //   4 B
    int*                nvD     = (int*)(ws + 491524);                  //   4 B
    unsigned long long* keepK   = (unsigned long long*)(ws + 492032);   //   1 KiB
    const size_t EDGE_OFF = 493568;
    unsigned int*       edges   = (unsigned int*)(ws + EDGE_OFF);
    size_t avail = (ws_size > EDGE_OFF + 16) ? (ws_size - EDGE_OFF) / 4 : 0;
    int ecap = (int)(avail > (size_t)ECAP_MAX ? (size_t)ECAP_MAX : avail);

    void* args[] = { (void*)&cls_conf, (void*)&bboxes, (void*)&out,
                     (void*)&keys, (void*)&partial, (void*)&sb, (void*)&order,
                     (void*)&edges, (void*)&ecntE, (void*)&nvD, (void*)&keepK,
                     (void*)&ecap };
    hipError_t err = hipLaunchCooperativeKernel((const void*)fused_kernel,
                                                dim3(NBLK), dim3(NTHR),
                                                args, 0, stream);
    if (err != hipSuccess) {
        // Fallback: verified 6-kernel pipeline (identical math).
        key_kernel<<<N_BOX / 256, 256, 0, stream>>>(cls_conf, keys, ecntE, nvD);
        rank_kernel<<<dim3(N_BOX / 256, NCH), 256, 0, stream>>>(keys, partial);
        scatter_kernel<<<N_BOX / 256, 256, 0, stream>>>(cls_conf, bboxes, partial, sb, order, nvD);
        pair_kernel<<<dim3(32, 128), 256, 0, stream>>>(sb, nvD, edges, ecntE, ecap);
        scan_kernel<<<1, 512, 0, stream>>>(edges, ecntE, nvD, sb, keepK, ecap);
        out_kernel<<<N_BOX / 256, 256, 0, stream>>>(sb, keepK, order, cls_conf, out);
    }
}

// Round 3
// 129.805 us; speedup vs baseline: 1.7395x; 1.7395x over previous
//
#include <hip/hip_runtime.h>
#include <math.h>

#define N_BOX 8192
#define NW 128              // 8192 / 64 words per keep-mask row
#define NTHR 512
#define LCAP 24576          // edges staged in LDS (96 KiB)
#define NPB 512             // pair blocks: 128 j-words x 4 i-splits
#define ISPL 4
#define NRB 128             // rank blocks: 16 element-chunks x 8 cand-chunks
#define WPB 8               // waves per block (512/64)
#define NWAVE (NPB * WPB)   // 4096 pair waves
#define SLOT 64             // edge slots per wave
#define WSPT (NWAVE / NTHR) // 8 wave-counts per stageB thread
#define NCH 8               // candidate chunks for rank stage
#define THR_C 0.7f
#define IOU_THR_C 0.5f
#define EPS_C 1e-9f

// SCALER = max(3508/1280, 2480/1280) computed in double then rounded to f32,
// matching numpy/jax float32 weak-typed scalar promotion.
__device__ __constant__ float kScaler = (float)(3508.0 / 1280.0);

// u64 key: ascending order == stable argsort(-masked_score). Unique (index in
// low bits). Invalid (-inf) keys sort strictly after all valid keys.
static __device__ __forceinline__ unsigned long long key_from(float c0, float c1, int i) {
    bool valid = (c0 > THR_C) || (c1 > THR_C);
    float ms = valid ? fmaxf(c0, c1) : -INFINITY;
    unsigned int u = __float_as_uint(ms);
    unsigned int m = (u & 0x80000000u) ? ~u : (u | 0x80000000u); // ascending map
    unsigned int d = ~m;                                          // descending key
    return ((unsigned long long)d << 32) | (unsigned int)i;
}

// ---------------------------------------------------------------------------
// Stage A (one launch, two block roles, no inter-stage dependency):
//  blocks [0, NPB): pair role. Block (w = b>>2, h = b&3) owns j-word w (64
//    boxes) and i-tiles h, h+4, ... over i in [0, (w+1)*64). For each pair
//    i<j (original indices), both valid, IoU>thr: emit ONE edge directed from
//    the higher-priority (smaller-key) box to the other. Edges go to the
//    wave's private 64-entry slot; wcnt[waveid] is ALWAYS written (no init
//    needed; overflow -> count > SLOT acts as fallback sentinel).
//  blocks [NPB, NPB+NRB): rank role. rank(i) = #{j : key_j < key_i} partial
//    counts over one 1024-candidate chunk, keys recomputed into LDS.
// ---------------------------------------------------------------------------
__global__ __launch_bounds__(NTHR) void stageA(const float* __restrict__ conf,
                                               const float* __restrict__ bboxes,
                                               int* __restrict__ partial,
                                               unsigned int* __restrict__ wcnt,
                                               unsigned int* __restrict__ wslot) {
    int b = blockIdx.x;
    int t = threadIdx.x;
    if (b < NPB) {
        __shared__ float4 cb[64];
        __shared__ float carea[64];
        __shared__ unsigned long long cbk[64];
        __shared__ unsigned long long jvS;
        int w = b >> 2;            // j-word 0..127
        int h = b & 3;             // i-tile phase 0..3
        if (t < 64) {              // exactly wave 0
            int j = (w << 6) + t;
            float4 c = ((const float4*)bboxes)[j];
            cb[t] = c;
            carea[t] = (c.z - c.x) * (c.w - c.y);
            float c0 = conf[2 * j], c1 = conf[2 * j + 1];
            cbk[t] = key_from(c0, c1, j);
            unsigned long long bv = __ballot((c0 > THR_C) || (c1 > THR_C));
            if (t == 0) jvS = bv;
        }
        __syncthreads();
        unsigned long long jv = jvS;
        int waveid = b * WPB + (t >> 6);
        int lane = t & 63;
        int wc = 0;                         // wave-uniform running edge count
        int jmax = (w << 6) + 63;
        int ntiles = (jmax + NTHR) / NTHR;  // ceil((jmax+1)/NTHR)
        for (int tt = h; tt < ntiles; tt += ISPL) {
            int i = tt * NTHR + t;
            unsigned long long bits = 0ull;
            unsigned long long ki = 0ull;
            // mask: valid j AND j > i (strict upper triangle in orig space)
            int rel = i - (w << 6);
            unsigned long long jm = jv;
            if (rel >= 63) jm = 0ull;
            else if (rel >= 0) jm &= ~((2ull << rel) - 1ull);
            if (jm) {
                float c0 = conf[2 * i], c1 = conf[2 * i + 1];
                bool iv = (c0 > THR_C) || (c1 > THR_C);
                if (iv) {
                    ki = key_from(c0, c1, i);
                    float4 r = ((const float4*)bboxes)[i];
                    float ra = (r.z - r.x) * (r.w - r.y);
#pragma unroll 8
                    for (int bb = 0; bb < 64; ++bb) {
                        float4 c = cb[bb];
                        float iw = fminf(r.z, c.z) - fmaxf(r.x, c.x);
                        float ih = fminf(r.w, c.w) - fmaxf(r.y, c.y);
                        iw = fmaxf(iw, 0.0f);
                        ih = fmaxf(ih, 0.0f);
                        float inter = iw * ih;
                        float iou = inter / (ra + carea[bb] - inter + EPS_C);
                        if (iou > IOU_THR_C) bits |= (1ull << bb);
                    }
                    bits &= jm;
                }
            }
            // wave-local compaction into the wave's private slot
            int ec = __popcll(bits);
            int pre = ec;
#pragma unroll
            for (int d = 1; d < 64; d <<= 1) {
                int vv = __shfl_up(pre, d, 64);
                if (lane >= d) pre += vv;
            }
            int tot = __shfl(pre, 63, 64);
            if (tot > 0) {
                int idx = wc + pre - ec;
                unsigned long long tb = bits;
                while (tb) {
                    int bb = __builtin_ctzll(tb); tb &= tb - 1;
                    if (idx < SLOT) {
                        int j = (w << 6) + bb;
                        // direction: smaller key = higher priority = suppressor
                        unsigned int e = (ki < cbk[bb])
                                         ? (((unsigned int)i << 13) | (unsigned int)j)
                                         : (((unsigned int)j << 13) | (unsigned int)i);
                        wslot[(size_t)waveid * SLOT + idx] = e;
                    }
                    ++idx;
                }
                wc += tot;
            }
        }
        if (lane == 0) wcnt[waveid] = (unsigned int)wc;  // >SLOT => sentinel
    } else {
        __shared__ unsigned long long ck[1024];          // 8 KiB candidate keys
        int rb = b - NPB;
        int ech = rb >> 3;        // element chunk 0..15
        int cch = rb & 7;         // candidate chunk 0..7
        for (int l = t; l < 1024; l += NTHR) {
            int j = (cch << 10) + l;
            ck[l] = key_from(conf[2 * j], conf[2 * j + 1], j);
        }
        __syncthreads();
        int i = (ech << 9) + t;
        unsigned long long ki = key_from(conf[2 * i], conf[2 * i + 1], i);
        const ulonglong2* ckp = (const ulonglong2*)ck;
        int a0 = 0, a1 = 0, a2 = 0, a3 = 0;
#pragma unroll 4
        for (int l = 0; l < 512; l += 2) {
            ulonglong2 u = ckp[l];
            ulonglong2 v = ckp[l + 1];
            a0 += (u.x < ki) ? 1 : 0;
            a1 += (u.y < ki) ? 1 : 0;
            a2 += (v.x < ki) ? 1 : 0;
            a3 += (v.y < ki) ? 1 : 0;
        }
        partial[cch * N_BOX + i] = (a0 + a1) + (a2 + a3);
    }
}

// ---------------------------------------------------------------------------
// Stage B (single block): valid mask -> prefix-sum wave counts -> gather
// edges to LDS -> Jacobi-iterated greedy fixpoint (verified logic; k_new ==
// k_old certifies exact greedy) -> rank-sum -> scattered (N,6) output.
// Fallback (any wcnt>SLOT or total>LCAP; never on this data): exact serial
// greedy over rank order via inverse permutation, IoU recomputed on the fly.
// ---------------------------------------------------------------------------
__global__ __launch_bounds__(NTHR) void stageB(const float* __restrict__ conf,
                                               const float* __restrict__ bboxes,
                                               const int* __restrict__ partial,
                                               const unsigned int* __restrict__ wcnt,
                                               const unsigned int* __restrict__ wslot,
                                               float* __restrict__ out) {
    __shared__ unsigned int eL[LCAP];                       // 96 KiB
    __shared__ unsigned long long kL[NW], tL[NW], vL[NW];   // 3 KiB
    __shared__ int wsum[NTHR];                              // 2 KiB
    __shared__ int chg[3];
    __shared__ int fbF, nvF;
    int t = threadIdx.x;
    if (t == 0) { fbF = 0; nvF = 0; chg[0] = 0; chg[1] = 0; chg[2] = 0; }
    // valid mask (original index space), coalesced + ballot
    for (int base = 0; base < N_BOX; base += NTHR) {
        int i = base + t;
        float c0 = conf[2 * i], c1 = conf[2 * i + 1];
        unsigned long long bv = __ballot((c0 > THR_C) || (c1 > THR_C));
        if ((t & 63) == 0) vL[i >> 6] = bv;
    }
    // per-thread wave-count partial sums
    int nq[WSPT], myo[WSPT];
    int s = 0;
    bool ov = false;
#pragma unroll
    for (int q = 0; q < WSPT; ++q) {
        int v = (int)wcnt[t * WSPT + q];
        nq[q] = v; myo[q] = s; s += v;
        if (v > SLOT) ov = true;
    }
    wsum[t] = s;
    __syncthreads();                       // vL, wsum, shared init done
    if (t < NW) kL[t] = vL[t];             // main-path keep init
    // Hillis-Steele inclusive scan over 512 partial sums
    for (int off = 1; off < NTHR; off <<= 1) {
        int v = (t >= off) ? wsum[t - off] : 0;
        __syncthreads();
        wsum[t] += v;
        __syncthreads();
    }
    int ebase = wsum[t] - s;               // exclusive base for this thread
    int totE = wsum[NTHR - 1];
    if (ov || totE > LCAP) fbF = 1;        // benign same-value race
    __syncthreads();
    int fb = fbF;
    if (!fb) {
        // gather this thread's 8 waves' edges into contiguous LDS
#pragma unroll
        for (int q = 0; q < WSPT; ++q) {
            int w2 = t * WSPT + q;
            int off = ebase + myo[q];
            for (int k = 0; k < nq[q]; ++k)
                eL[off + k] = wslot[(size_t)w2 * SLOT + k];
        }
    }
    __syncthreads();
    if (!fb) {
        for (int it = 0; it < N_BOX; ++it) {
            if (t < NW) tL[t] = 0ull;
            __syncthreads();
            for (int e = t; e < totE; e += NTHR) {
                unsigned int ed = eL[e];
                int src = (int)(ed >> 13);
                if ((kL[src >> 6] >> (src & 63)) & 1ull) {
                    int tg = (int)(ed & 8191u);
                    atomicOr(&tL[tg >> 6], 1ull << (tg & 63));
                }
            }
            __syncthreads();
            if (t < NW) {
                unsigned long long nk = vL[t] & ~tL[t];
                if (nk != kL[t]) chg[it % 3] = 1;
                kL[t] = nk;
            }
            if (t == 0) chg[(it + 2) % 3] = 0;   // reset 2 barriers before reuse
            __syncthreads();
            if (chg[it % 3] == 0) break;         // uniform: read after barrier
        }
    } else {
        // fallback: build inverse permutation sinv[rank]=orig in eL, serial
        // greedy over rank order (one wave), then map kept ranks -> orig bits
        unsigned int* sinv = eL;
        for (int base = 0; base < N_BOX; base += NTHR) {
            int i = base + t;
            int r = 0;
#pragma unroll
            for (int c = 0; c < NCH; ++c) r += partial[c * N_BOX + i];
            sinv[r] = (unsigned int)i;
        }
        if (t < NW) { atomicAdd(&nvF, __popcll(vL[t])); tL[t] = 0ull; kL[t] = 0ull; }
        __syncthreads();
        int nv = nvF;
        if (t < 64) {
            for (int a = 0; a < nv - 1; ++a) {
                bool rem = (tL[a >> 6] >> (a & 63)) & 1ull;
                if (!rem) {
                    float4 r = ((const float4*)bboxes)[sinv[a]];
                    float ra = (r.z - r.x) * (r.w - r.y);
                    for (int b2 = a + 1 + t; b2 < nv; b2 += 64) {
                        float4 c = ((const float4*)bboxes)[sinv[b2]];
                        float ca = (c.z - c.x) * (c.w - c.y);
                        float iw = fminf(r.z, c.z) - fmaxf(r.x, c.x);
                        float ih = fminf(r.w, c.w) - fmaxf(r.y, c.y);
                        iw = fmaxf(iw, 0.0f);
                        ih = fmaxf(ih, 0.0f);
                        float inter = iw * ih;
                        float iou = inter / (ra + ca - inter + EPS_C);
                        if (iou > IOU_THR_C) atomicOr(&tL[b2 >> 6], 1ull << (b2 & 63));
                    }
                }
            }
        }
        __syncthreads();
        for (int a = t; a < nv; a += NTHR) {
            if (!((tL[a >> 6] >> (a & 63)) & 1ull)) {
                int ia = (int)sinv[a];
                atomicOr(&kL[ia >> 6], 1ull << (ia & 63));
            }
        }
    }
    __syncthreads();
    // output: row rank(i) <- kept ? [bbox_i*SCALER, conf_i] : zeros.
    // rank is a bijection, so every output row is written exactly once.
    // Suppressed/invalid rows are exactly 0.0 in the reference (positive
    // values * 0.0), so literal zeros are bit-identical.
    for (int base = 0; base < N_BOX; base += NTHR) {
        int i = base + t;
        int r = 0;
#pragma unroll
        for (int c = 0; c < NCH; ++c) r += partial[c * N_BOX + i];
        bool kept = (kL[i >> 6] >> (i & 63)) & 1ull;
        if (kept) {
            float4 bx = ((const float4*)bboxes)[i];
            out[r * 6 + 0] = bx.x * kScaler;
            out[r * 6 + 1] = bx.y * kScaler;
            out[r * 6 + 2] = bx.z * kScaler;
            out[r * 6 + 3] = bx.w * kScaler;
            out[r * 6 + 4] = conf[2 * i];
            out[r * 6 + 5] = conf[2 * i + 1];
        } else {
            out[r * 6 + 0] = 0.0f;
            out[r * 6 + 1] = 0.0f;
            out[r * 6 + 2] = 0.0f;
            out[r * 6 + 3] = 0.0f;
            out[r * 6 + 4] = 0.0f;
            out[r * 6 + 5] = 0.0f;
        }
    }
}

extern "C" void kernel_launch(void* const* d_in, const int* in_sizes, int n_in,
                              void* d_out, int out_size, void* d_ws, size_t ws_size,
                              hipStream_t stream) {
    const float* cls_conf = (const float*)d_in[0];   // (8192, 2)
    const float* bboxes   = (const float*)d_in[1];   // (8192, 4)
    float* out = (float*)d_out;                      // (8192, 6)

    char* ws = (char*)d_ws;
    int*          partial = (int*)(ws + 0);                    // 256 KiB
    unsigned int* wcnt    = (unsigned int*)(ws + 262144);      //  16 KiB
    unsigned int* wslot   = (unsigned int*)(ws + 278528);      //   1 MiB
    (void)ws_size; (void)in_sizes; (void)n_in; (void)out_size;

    stageA<<<NPB + NRB, NTHR, 0, stream>>>(cls_conf, bboxes, partial, wcnt, wslot);
    stageB<<<1, NTHR, 0, stream>>>(cls_conf, bboxes, partial, wcnt, wslot, out);
}

// Round 4
// 116.897 us; speedup vs baseline: 1.9315x; 1.1104x over previous
//
#include <hip/hip_runtime.h>
#include <math.h>

#define N_BOX 8192
#define NW 128              // 8192 / 64 words per keep-mask row
#define NTHR 512
#define LCAP 24576          // edges staged in LDS (96 KiB)
#define NPB 512             // pair blocks: 128 j-words x 4 tile slots
#define TPW 4               // tile slots per j-word
#define RPT 4               // rows per thread (tile = NTHR*RPT = 2048 rows)
#define NRB 128             // rank blocks: 16 element-chunks x 8 cand-chunks
#define WPB 8               // waves per block (512/64)
#define NWAVE (NPB * WPB)   // 4096 pair waves
#define SLOT 128            // edge slots per wave
#define WSPT (NWAVE / NTHR) // 8 wave-counts per stageB thread
#define NCH 8               // candidate chunks for rank stage
#define THR_C 0.7f
#define IOU_THR_C 0.5f
#define EPS_C 1e-9f

// SCALER = max(3508/1280, 2480/1280) computed in double then rounded to f32,
// matching numpy/jax float32 weak-typed scalar promotion.
__device__ __constant__ float kScaler = (float)(3508.0 / 1280.0);

// u64 key: ascending order == stable argsort(-masked_score). Unique (index in
// low bits). Invalid (-inf) keys sort strictly after all valid keys.
static __device__ __forceinline__ unsigned long long key_from(float c0, float c1, int i) {
    bool valid = (c0 > THR_C) || (c1 > THR_C);
    float ms = valid ? fmaxf(c0, c1) : -INFINITY;
    unsigned int u = __float_as_uint(ms);
    unsigned int m = (u & 0x80000000u) ? ~u : (u | 0x80000000u); // ascending map
    unsigned int d = ~m;                                          // descending key
    return ((unsigned long long)d << 32) | (unsigned int)i;
}

// ---------------------------------------------------------------------------
// Stage A (one launch, two block roles, no inter-stage dependency):
//  blocks [0, NPB): pair role. Block (w = b>>2, h = b&3) owns j-word w (64
//    boxes) and i-tile h (2048 rows, 4/thread in registers); blocks with
//    h >= ntiles(w) write zero wave-counts and exit. For each pair i<j, both
//    valid, IoU>thr: emit ONE edge directed from the higher-priority
//    (smaller-key) box. Division screen: iou>0.5 => inter > (ra+ca)/3 in real
//    arithmetic, so inter > 0.2*(ra+ca) is a conservative gate with 1.67x
//    margin; the exact reference division runs only for gated pairs ->
//    bit-identical decisions. Edges go to the wave's private slot; wcnt is
//    ALWAYS written (no init; count>SLOT acts as fallback sentinel).
//  blocks [NPB, NPB+NRB): rank role. rank(i) = #{j : key_j < key_i} partial
//    counts over one 1024-candidate chunk, keys recomputed into LDS.
// ---------------------------------------------------------------------------
__global__ __launch_bounds__(NTHR) void stageA(const float* __restrict__ conf,
                                               const float* __restrict__ bboxes,
                                               int* __restrict__ partial,
                                               unsigned int* __restrict__ wcnt,
                                               unsigned int* __restrict__ wslot) {
    int b = blockIdx.x;
    int t = threadIdx.x;
    if (b < NPB) {
        int w = b >> 2;                    // j-word 0..127
        int h = b & (TPW - 1);             // tile slot 0..3
        int ntiles = (w >> 5) + 1;         // tiles covering rows [0, w*64+63]
        int waveid = b * WPB + (t >> 6);
        int lane = t & 63;
        if (h >= ntiles) {                 // no work: still publish zero counts
            if (lane == 0) wcnt[waveid] = 0u;
            return;
        }
        __shared__ float4 cb[64];
        __shared__ float carea[64];
        __shared__ unsigned long long cbk[64];
        __shared__ unsigned long long jvS;
        if (t < 64) {                      // exactly wave 0
            int j = (w << 6) + t;
            float4 c = ((const float4*)bboxes)[j];
            cb[t] = c;
            carea[t] = (c.z - c.x) * (c.w - c.y);
            float2 cc = ((const float2*)conf)[j];
            cbk[t] = key_from(cc.x, cc.y, j);
            unsigned long long bv = __ballot((cc.x > THR_C) || (cc.y > THR_C));
            if (t == 0) jvS = bv;
        }
        __syncthreads();
        unsigned long long jv = jvS;
        int ibase = h << 11;               // h * 2048
        // 4 register-resident rows per thread (loads always in-bounds)
        float4 rb_[RPT];
        float ra_[RPT];
        unsigned long long ki_[RPT], jm_[RPT];
#pragma unroll
        for (int q = 0; q < RPT; ++q) {
            int i = ibase + (q << 9) + t;
            int rel = i - (w << 6);
            unsigned long long jm = jv;    // valid j AND j > i
            if (rel >= 63) jm = 0ull;
            else if (rel >= 0) jm &= ~((2ull << rel) - 1ull);
            float2 cc = ((const float2*)conf)[i];
            if (!((cc.x > THR_C) || (cc.y > THR_C))) jm = 0ull;
            jm_[q] = jm;
            float4 r = ((const float4*)bboxes)[i];
            rb_[q] = r;
            ra_[q] = (r.z - r.x) * (r.w - r.y);
            ki_[q] = key_from(cc.x, cc.y, i);
        }
        int wc = 0;                        // wave-uniform running edge count
        bool wave_has = __any((jm_[0] | jm_[1] | jm_[2] | jm_[3]) != 0ull);
        if (wave_has) {
            unsigned long long bits[RPT] = {0ull, 0ull, 0ull, 0ull};
            for (int bb = 0; bb < 64; ++bb) {
                float4 c = cb[bb];
                float ca = carea[bb];
#pragma unroll
                for (int q = 0; q < RPT; ++q) {
                    float iw = fminf(rb_[q].z, c.z) - fmaxf(rb_[q].x, c.x);
                    float ih = fminf(rb_[q].w, c.w) - fmaxf(rb_[q].y, c.y);
                    iw = fmaxf(iw, 0.0f);
                    ih = fmaxf(ih, 0.0f);
                    float inter = iw * ih;
                    float sab = ra_[q] + ca;
                    if (inter > 0.2f * sab) {   // conservative: never drops a hit
                        // exact reference arithmetic (bit-identical decision)
                        float iou = inter / (ra_[q] + ca - inter + EPS_C);
                        if (iou > IOU_THR_C) bits[q] |= (1ull << bb);
                    }
                }
            }
#pragma unroll
            for (int q = 0; q < RPT; ++q) {
                unsigned long long eb = bits[q] & jm_[q];
                if (__any(eb != 0ull)) {
                    int ec = __popcll(eb);
                    int pre = ec;
#pragma unroll
                    for (int d = 1; d < 64; d <<= 1) {
                        int vv = __shfl_up(pre, d, 64);
                        if (lane >= d) pre += vv;
                    }
                    int tot = __shfl(pre, 63, 64);
                    int idx = wc + pre - ec;
                    unsigned long long tb = eb;
                    int i = ibase + (q << 9) + t;
                    while (tb) {
                        int bb = __builtin_ctzll(tb); tb &= tb - 1;
                        if (idx < SLOT) {
                            int j = (w << 6) + bb;
                            // smaller key = higher priority = suppressor
                            unsigned int e = (ki_[q] < cbk[bb])
                                             ? (((unsigned int)i << 13) | (unsigned int)j)
                                             : (((unsigned int)j << 13) | (unsigned int)i);
                            wslot[(size_t)waveid * SLOT + idx] = e;
                        }
                        ++idx;
                    }
                    wc += tot;
                }
            }
        }
        if (lane == 0) wcnt[waveid] = (unsigned int)wc;  // >SLOT => sentinel
    } else {
        __shared__ unsigned long long ck[1024];          // 8 KiB candidate keys
        int rb = b - NPB;
        int ech = rb >> 3;        // element chunk 0..15
        int cch = rb & 7;         // candidate chunk 0..7
        for (int l = t; l < 1024; l += NTHR) {
            int j = (cch << 10) + l;
            float2 cc = ((const float2*)conf)[j];
            ck[l] = key_from(cc.x, cc.y, j);
        }
        __syncthreads();
        int i = (ech << 9) + t;
        float2 ci = ((const float2*)conf)[i];
        unsigned long long ki = key_from(ci.x, ci.y, i);
        const ulonglong2* ckp = (const ulonglong2*)ck;
        int a0 = 0, a1 = 0, a2 = 0, a3 = 0;
#pragma unroll 4
        for (int l = 0; l < 512; l += 2) {
            ulonglong2 u = ckp[l];
            ulonglong2 v = ckp[l + 1];
            a0 += (u.x < ki) ? 1 : 0;
            a1 += (u.y < ki) ? 1 : 0;
            a2 += (v.x < ki) ? 1 : 0;
            a3 += (v.y < ki) ? 1 : 0;
        }
        partial[cch * N_BOX + i] = (a0 + a1) + (a2 + a3);
    }
}

// ---------------------------------------------------------------------------
// Stage B (single block): valid mask -> prefix-sum wave counts -> gather
// edges to LDS -> Jacobi-iterated greedy fixpoint (verified logic; k_new ==
// k_old certifies exact greedy) -> rank-sum -> scattered (N,6) output.
// Fallback (any wcnt>SLOT or total>LCAP; never on this data): exact serial
// greedy over rank order via inverse permutation, IoU recomputed on the fly.
// ---------------------------------------------------------------------------
__global__ __launch_bounds__(NTHR) void stageB(const float* __restrict__ conf,
                                               const float* __restrict__ bboxes,
                                               const int* __restrict__ partial,
                                               const unsigned int* __restrict__ wcnt,
                                               const unsigned int* __restrict__ wslot,
                                               float* __restrict__ out) {
    __shared__ unsigned int eL[LCAP];                       // 96 KiB
    __shared__ unsigned long long kL[NW], tL[NW], vL[NW];   // 3 KiB
    __shared__ int wsum[NTHR];                              // 2 KiB
    __shared__ int chg[3];
    __shared__ int fbF, nvF;
    int t = threadIdx.x;
    if (t == 0) { fbF = 0; nvF = 0; chg[0] = 0; chg[1] = 0; chg[2] = 0; }
    // valid mask (original index space), coalesced + ballot
    for (int base = 0; base < N_BOX; base += NTHR) {
        int i = base + t;
        float2 cc = ((const float2*)conf)[i];
        unsigned long long bv = __ballot((cc.x > THR_C) || (cc.y > THR_C));
        if ((t & 63) == 0) vL[i >> 6] = bv;
    }
    // per-thread wave-count partial sums
    int nq[WSPT], myo[WSPT];
    int s = 0;
    bool ov = false;
#pragma unroll
    for (int q = 0; q < WSPT; ++q) {
        int v = (int)wcnt[t * WSPT + q];
        nq[q] = v; myo[q] = s; s += v;
        if (v > SLOT) ov = true;
    }
    wsum[t] = s;
    __syncthreads();                       // vL, wsum, shared init done
    if (t < NW) kL[t] = vL[t];             // main-path keep init
    // Hillis-Steele inclusive scan over 512 partial sums
    for (int off = 1; off < NTHR; off <<= 1) {
        int v = (t >= off) ? wsum[t - off] : 0;
        __syncthreads();
        wsum[t] += v;
        __syncthreads();
    }
    int ebase = wsum[t] - s;               // exclusive base for this thread
    int totE = wsum[NTHR - 1];
    if (ov || totE > LCAP) fbF = 1;        // benign same-value race
    __syncthreads();
    int fb = fbF;
    if (!fb) {
        // gather this thread's 8 waves' edges into contiguous LDS
#pragma unroll
        for (int q = 0; q < WSPT; ++q) {
            int w2 = t * WSPT + q;
            int off = ebase + myo[q];
            for (int k = 0; k < nq[q]; ++k)
                eL[off + k] = wslot[(size_t)w2 * SLOT + k];
        }
    }
    __syncthreads();
    if (!fb) {
        for (int it = 0; it < N_BOX; ++it) {
            if (t < NW) tL[t] = 0ull;
            __syncthreads();
            for (int e = t; e < totE; e += NTHR) {
                unsigned int ed = eL[e];
                int src = (int)(ed >> 13);
                if ((kL[src >> 6] >> (src & 63)) & 1ull) {
                    int tg = (int)(ed & 8191u);
                    atomicOr(&tL[tg >> 6], 1ull << (tg & 63));
                }
            }
            __syncthreads();
            if (t < NW) {
                unsigned long long nk = vL[t] & ~tL[t];
                if (nk != kL[t]) chg[it % 3] = 1;
                kL[t] = nk;
            }
            if (t == 0) chg[(it + 2) % 3] = 0;   // reset 2 barriers before reuse
            __syncthreads();
            if (chg[it % 3] == 0) break;         // uniform: read after barrier
        }
    } else {
        // fallback: build inverse permutation sinv[rank]=orig in eL, serial
        // greedy over rank order (one wave), then map kept ranks -> orig bits
        unsigned int* sinv = eL;
        for (int base = 0; base < N_BOX; base += NTHR) {
            int i = base + t;
            int r = 0;
#pragma unroll
            for (int c = 0; c < NCH; ++c) r += partial[c * N_BOX + i];
            sinv[r] = (unsigned int)i;
        }
        if (t < NW) { atomicAdd(&nvF, __popcll(vL[t])); tL[t] = 0ull; kL[t] = 0ull; }
        __syncthreads();
        int nv = nvF;
        if (t < 64) {
            for (int a = 0; a < nv - 1; ++a) {
                bool rem = (tL[a >> 6] >> (a & 63)) & 1ull;
                if (!rem) {
                    float4 r = ((const float4*)bboxes)[sinv[a]];
                    float ra = (r.z - r.x) * (r.w - r.y);
                    for (int b2 = a + 1 + t; b2 < nv; b2 += 64) {
                        float4 c = ((const float4*)bboxes)[sinv[b2]];
                        float ca = (c.z - c.x) * (c.w - c.y);
                        float iw = fminf(r.z, c.z) - fmaxf(r.x, c.x);
                        float ih = fminf(r.w, c.w) - fmaxf(r.y, c.y);
                        iw = fmaxf(iw, 0.0f);
                        ih = fmaxf(ih, 0.0f);
                        float inter = iw * ih;
                        float iou = inter / (ra + ca - inter + EPS_C);
                        if (iou > IOU_THR_C) atomicOr(&tL[b2 >> 6], 1ull << (b2 & 63));
                    }
                }
            }
        }
        __syncthreads();
        for (int a = t; a < nv; a += NTHR) {
            if (!((tL[a >> 6] >> (a & 63)) & 1ull)) {
                int ia = (int)sinv[a];
                atomicOr(&kL[ia >> 6], 1ull << (ia & 63));
            }
        }
    }
    __syncthreads();
    // output: row rank(i) <- kept ? [bbox_i*SCALER, conf_i] : zeros.
    // rank is a bijection, so every output row is written exactly once.
    // Suppressed/invalid rows are exactly 0.0 in the reference (positive
    // values * 0.0), so literal zeros are bit-identical.
    for (int base = 0; base < N_BOX; base += NTHR) {
        int i = base + t;
        int r = 0;
#pragma unroll
        for (int c = 0; c < NCH; ++c) r += partial[c * N_BOX + i];
        bool kept = (kL[i >> 6] >> (i & 63)) & 1ull;
        if (kept) {
            float4 bx = ((const float4*)bboxes)[i];
            float2 cc = ((const float2*)conf)[i];
            out[r * 6 + 0] = bx.x * kScaler;
            out[r * 6 + 1] = bx.y * kScaler;
            out[r * 6 + 2] = bx.z * kScaler;
            out[r * 6 + 3] = bx.w * kScaler;
            out[r * 6 + 4] = cc.x;
            out[r * 6 + 5] = cc.y;
        } else {
            out[r * 6 + 0] = 0.0f;
            out[r * 6 + 1] = 0.0f;
            out[r * 6 + 2] = 0.0f;
            out[r * 6 + 3] = 0.0f;
            out[r * 6 + 4] = 0.0f;
            out[r * 6 + 5] = 0.0f;
        }
    }
}

extern "C" void kernel_launch(void* const* d_in, const int* in_sizes, int n_in,
                              void* d_out, int out_size, void* d_ws, size_t ws_size,
                              hipStream_t stream) {
    const float* cls_conf = (const float*)d_in[0];   // (8192, 2)
    const float* bboxes   = (const float*)d_in[1];   // (8192, 4)
    float* out = (float*)d_out;                      // (8192, 6)

    char* ws = (char*)d_ws;
    int*          partial = (int*)(ws + 0);                    // 256 KiB
    unsigned int* wcnt    = (unsigned int*)(ws + 262144);      //  16 KiB
    unsigned int* wslot   = (unsigned int*)(ws + 278528);      //   2 MiB
    (void)ws_size; (void)in_sizes; (void)n_in; (void)out_size;

    stageA<<<NPB + NRB, NTHR, 0, stream>>>(cls_conf, bboxes, partial, wcnt, wslot);
    stageB<<<1, NTHR, 0, stream>>>(cls_conf, bboxes, partial, wcnt, wslot, out);
}